// Round 15
// baseline (149.692 us; speedup 1.0000x reference)
//
#include <hip/hip_runtime.h>
#include <hip/hip_bf16.h>
#include <math.h>

#define B_CONST 256
#define T_CONST 8192
#define P_CONST 16
#define H_CONST 1024

typedef __bf16 bf16x8 __attribute__((ext_vector_type(8)));
typedef __bf16 bf16x4 __attribute__((ext_vector_type(4)));
typedef float  f32x4  __attribute__((ext_vector_type(4)));
typedef int    i32x4  __attribute__((ext_vector_type(4)));
typedef int    i32x8  __attribute__((ext_vector_type(8)));

typedef __attribute__((address_space(3))) void       as3_void;
typedef const __attribute__((address_space(1))) void as1_cvoid;

__device__ __forceinline__ void gload_lds16(const void* g, void* l) {
    __builtin_amdgcn_global_load_lds((as1_cvoid*)g, (as3_void*)l, 16, 0, 0);
}

// fast gelu: x * sigmoid(1.5957691 * x * (1 + 0.044715 x^2))
__device__ __forceinline__ float gelu_fast(float x) {
    float z = 1.5957691216057308f * x * __builtin_fmaf(0.044715f, x * x, 1.0f);
    return x * __builtin_amdgcn_rcpf(1.0f + __expf(-z));
}

// fp4 e2m1 quantize (round to nearest of {0,.5,1,1.5,2,3,4,6}, sign bit 3)
__device__ __forceinline__ unsigned int f2fp4(float v) {
    float a = __builtin_fabsf(v);
    unsigned s = (__builtin_bit_cast(unsigned int, v) >> 31) << 3;
    unsigned c = (a < 0.25f) ? 0u : (a < 0.75f) ? 1u : (a < 1.25f) ? 2u :
                 (a < 1.75f) ? 3u : (a < 2.5f)  ? 4u : (a < 3.5f)  ? 5u :
                 (a < 5.0f)  ? 6u : 7u;
    return s | c;
}
__device__ __forceinline__ unsigned short pack_fp4x4(f32x4 v) {
    return (unsigned short)(f2fp4(v[0]) | (f2fp4(v[1]) << 4) |
                            (f2fp4(v[2]) << 8) | (f2fp4(v[3]) << 12));
}

// E8M0 scales, replicated bytes (op_sel=0 -> byte 0)
#define SC_UNIT 0x7F7F7F7F   // 2^0
#define SC_W32  0x7A7A7A7A   // 2^-5 (weights pre-scaled x32 at prep)

// ------------- kernel 1: per-batch valid count via ballot binary search --------
__global__ __launch_bounds__(64) void k_valid(const float* __restrict__ x,
                                              int* __restrict__ valid) {
    const int b = blockIdx.x;
    const int l = threadIdx.x;
    const float* m = x + (size_t)b * (T_CONST * 2) + 1;   // mask[t] = m[2t]
    bool one1 = m[(size_t)2 * (l * 128)] > 0.5f;
    int c1 = __popcll(__ballot(one1));
    int v = 0;
    if (c1 > 0) {
        int base = (c1 - 1) * 128;
        bool one2 = m[(size_t)2 * (base + l * 2)] > 0.5f;
        int c2 = __popcll(__ballot(one2));          // >= 1
        int tp = base + 2 * c2 - 1;
        v = (m[(size_t)2 * tp] > 0.5f) ? (base + 2 * c2) : (base + 2 * c2 - 1);
    }
    if (l == 0) valid[b] = v;
}

// ------------- fused prep: scan (blk 0) + w1t bf16 (blk 1-4) + fp4 transposes --
// blk 5..1028: w2 -> w2t fp4 (x32, packed 2/byte); blk 1029..2052: w3 -> w3t.
__global__ __launch_bounds__(256) void k_prep(
    const int* __restrict__ valid, int* __restrict__ pc, int* __restrict__ starts,
    int* __restrict__ cum, float* __restrict__ out_pc,
    const float* __restrict__ w1, __bf16* __restrict__ w1t,
    const float* __restrict__ w2, unsigned char* __restrict__ w2t,
    const float* __restrict__ w3, unsigned char* __restrict__ w3t) {
    __shared__ int s[B_CONST];
    __shared__ float tile[32][33];
    const int bid = blockIdx.x;
    const int t = threadIdx.x;
    if (bid == 0) {
        int v = valid[t];
        int p = (v + P_CONST - 1) / P_CONST;
        s[t] = p;
        __syncthreads();
        for (int off = 1; off < B_CONST; off <<= 1) {
            int add = (t >= off) ? s[t - off] : 0;
            __syncthreads();
            s[t] += add;
            __syncthreads();
        }
        pc[t] = p;
        cum[t] = s[t];
        starts[t] = s[t] - p;
        out_pc[t] = (float)p;
    } else if (bid <= 4) {
        int n = (bid - 1) * 256 + t;
        for (int k = 0; k < 32; ++k)
            w1t[n * 32 + k] = (k < 16) ? (__bf16)w1[k * H_CONST + n] : (__bf16)0.f;
    } else {
        int fid = bid - 5;
        const float* W = w2; unsigned char* WT = w2t;
        if (fid >= 1024) { W = w3; WT = w3t; fid -= 1024; }
        const int n0 = (fid & 31) * 32, k0 = (fid >> 5) * 32;
        const int c = t & 31, r0 = t >> 5;
        for (int r = r0; r < 32; r += 8)
            tile[r][c] = W[(size_t)(k0 + r) * H_CONST + n0 + c];
        __syncthreads();
        // write fp4-packed transposed: row n (32) x 16 bytes (32 k / 2)
        const int nl = t >> 3;          // 0..31
        const int b0 = t & 7;           // handles bytes b0 and b0+8
        unsigned char* dst = WT + (size_t)(n0 + nl) * (H_CONST / 2) + (k0 >> 1);
#pragma unroll
        for (int h = 0; h < 2; ++h) {
            int b = b0 + h * 8;
            unsigned lo = f2fp4(32.f * tile[2 * b][nl]);
            unsigned hi = f2fp4(32.f * tile[2 * b + 1][nl]);
            dst[b] = (unsigned char)(lo | (hi << 4));
        }
    }
}

// ---------------- layer-1 fused gather+GEMM (K=32 bf16), fp4 output ------------
__global__ __launch_bounds__(256) void k_l1_fused(
    const float* __restrict__ x, const int* __restrict__ valid,
    const int* __restrict__ cum, const int* __restrict__ starts,
    const __bf16* __restrict__ w1t, const float* __restrict__ bias,
    unsigned char* __restrict__ C, int total) {
    __shared__ __bf16 As[128][32];
    __shared__ __bf16 Bs[128][32];

    const int lane = threadIdx.x & 63;
    const int wid  = threadIdx.x >> 6;
    const int wr = wid >> 1, wc = wid & 1;

    const int nwg_x = gridDim.x;
    const int orig = blockIdx.y * nwg_x + blockIdx.x;
    const int cpx = (nwg_x * gridDim.y) >> 3;
    const int wgid = (orig & 7) * cpx + (orig >> 3);
    const int brow = (wgid / nwg_x) * 128;
    const int bcol = (wgid % nwg_x) * 128;

    const int sr = lane >> 2;
    const int sc = (lane & 3) * 8;
    const size_t b_base = (size_t)(bcol + wid * 16 + sr) * 32 + sc;
    gload_lds16(w1t + b_base,           &Bs[wid * 16][0]);
    gload_lds16(w1t + b_base + 64 * 32, &Bs[64 + wid * 16][0]);

    {
        const int r  = threadIdx.x >> 1;
        const int ch = threadIdx.x & 1;
        const int j  = brow + r;
        int lo = 0, hi = B_CONST - 1;
        while (lo < hi) { int mid = (lo + hi) >> 1; if (cum[mid] > j) hi = mid; else lo = mid + 1; }
        const int b = lo;
        const int p = j - starts[b];
        __bf16 vals[16];
        if (ch == 0) {
            const int vb = valid[b];
            const float* xb = x + (size_t)b * (T_CONST * 2) + 32 * p;
#pragma unroll
            for (int i = 0; i < 8; ++i) {
                float4 v = *(const float4*)(xb + 4 * i);
                int i0 = p * 16 + 2 * i;
                vals[2 * i]     = (__bf16)((i0 < vb)     ? v.x : 0.f);
                vals[2 * i + 1] = (__bf16)((i0 + 1 < vb) ? v.z : 0.f);
            }
        } else {
#pragma unroll
            for (int i = 0; i < 16; ++i) vals[i] = (__bf16)0.f;
        }
        *(bf16x8*)&As[r][ch * 16]     = *(bf16x8*)&vals[0];
        *(bf16x8*)&As[r][ch * 16 + 8] = *(bf16x8*)&vals[8];
    }
    __syncthreads();

    const int lr = lane & 15;
    const int lk = (lane >> 4) * 8;

    f32x4 acc[4][4];
#pragma unroll
    for (int i = 0; i < 4; ++i)
#pragma unroll
        for (int j = 0; j < 4; ++j)
            acc[i][j] = (f32x4){0.f, 0.f, 0.f, 0.f};

    bf16x8 af[4], bfr[4];
#pragma unroll
    for (int mf = 0; mf < 4; ++mf)
        af[mf] = *(const bf16x8*)&As[wr * 64 + mf * 16 + lr][lk];
#pragma unroll
    for (int nf = 0; nf < 4; ++nf)
        bfr[nf] = *(const bf16x8*)&Bs[wc * 64 + nf * 16 + lr][lk];
#pragma unroll
    for (int mf = 0; mf < 4; ++mf)
#pragma unroll
        for (int nf = 0; nf < 4; ++nf)
            acc[mf][nf] = __builtin_amdgcn_mfma_f32_16x16x32_bf16(
                bfr[nf], af[mf], acc[mf][nf], 0, 0, 0);

    const int c4 = (lane >> 4) << 2;
#pragma unroll
    for (int nf = 0; nf < 4; ++nf) {
        const int col0 = bcol + wc * 64 + nf * 16 + c4;
        const f32x4 bv = *(const f32x4*)&bias[col0];
#pragma unroll
        for (int mf = 0; mf < 4; ++mf) {
            const int row = brow + wr * 64 + mf * 16 + lr;
            f32x4 v = acc[mf][nf] + bv;
#pragma unroll
            for (int rr = 0; rr < 4; ++rr) v[rr] = gelu_fast(v[rr]);
            *(unsigned short*)&C[((size_t)row * H_CONST + col0) >> 1] = pack_fp4x4(v);
        }
    }
}

// ---------------- big GEMM: MX-fp4 K=128, dbuf + STREAMED frag reads -----------
// Dbuf (32 KiB) makes streamed reads legal (reads from buf, STG targets buf^1
// -> no WAR with in-flight stage). Inner loop: preload bfr[4] (32 VGPR), then
// per-mf {1 ds_read af (8 VGPR) -> 4 MFMA}. Live ~= 64 acc + 40 frag + addr
// ~= 115 VGPR -> natural 4 waves/SIMD -> 4 blocks/CU (16 waves/CU, +33% TLP
// over the 3-block register-walled R13/R14). No min-wave clamp (R11 lesson).
// One barrier/tile; hazards: reads of buf need STG(buf) from t-1 (drained by
// t-1's barrier); STG(buf^1) vs t-1 readers (lgkm-drained at same barrier).
template <bool GELU, bool OUT32>
__global__ __launch_bounds__(256) void k_gemm_mx4(
    const unsigned char* __restrict__ A, const unsigned char* __restrict__ WT,
    const float* __restrict__ bias, void* __restrict__ Cout,
    int M, int N, int K) {
    __shared__ unsigned char As[2][128][64];   // 16 KiB
    __shared__ unsigned char Bs[2][128][64];   // 16 KiB

    const int lane = threadIdx.x & 63;
    const int wid  = threadIdx.x >> 6;
    const int wr = wid >> 1, wc = wid & 1;

    const int nwg_x = gridDim.x;
    const int orig = blockIdx.y * nwg_x + blockIdx.x;
    const int cpx = (nwg_x * gridDim.y) >> 3;   // nwg = 2056, %8 == 0
    const int wgid = (orig & 7) * cpx + (orig >> 3);
    const int brow = (wgid / nwg_x) * 128;
    const int bcol = (wgid % nwg_x) * 128;

    f32x4 acc[4][4];
#pragma unroll
    for (int i = 0; i < 4; ++i)
#pragma unroll
        for (int j = 0; j < 4; ++j)
            acc[i][j] = (f32x4){0.f, 0.f, 0.f, 0.f};

    // staging: per K-tile each wave covers 32 rows x 64 B = 2 loads per matrix.
    // 1-KB load: lane l -> row l>>2 (16 rows), slot l&3. Pre-swizzled global
    // source: fetch slot (l&3) ^ ((row>>1)&3) = (l&3) ^ ((l>>3)&3).
    const int KB = K >> 1;                           // 512 bytes/row
    const int srow = lane >> 2;
    const int sgrp = 16 * ((lane & 3) ^ ((lane >> 3) & 3));
    const unsigned char* Ab = A  + (size_t)(brow + wid * 32 + srow) * KB + sgrp;
    const unsigned char* Bb = WT + (size_t)(bcol + wid * 32 + srow) * KB + sgrp;
    const size_t r16 = (size_t)16 * KB;

#define STG(buf, ko)                                                  \
    do {                                                              \
        gload_lds16(Ab + (ko),       &As[buf][wid * 32][0]);          \
        gload_lds16(Ab + r16 + (ko), &As[buf][wid * 32 + 16][0]);     \
        gload_lds16(Bb + (ko),       &Bs[buf][wid * 32][0]);          \
        gload_lds16(Bb + r16 + (ko), &Bs[buf][wid * 32 + 16][0]);     \
    } while (0)

    // fragment reads: op-row = frag*16 + (lane&15); lane's 32 k-elems = 16 B
    // at slot lane>>4, swizzled with (row>>1)&3 = ((lane&15)>>1)&3.
    const int lr = lane & 15;
    const int cb = ((lane >> 4) ^ ((lr >> 1) & 3)) << 4;

    const int nt = K >> 7;   // 8 K-tiles of 128
    STG(0, 0);
    __syncthreads();         // tile-0 loads landed

    for (int t = 0; t < nt; ++t) {
        const int buf = t & 1;
        if (t + 1 < nt) STG(buf ^ 1, (t + 1) * 64);   // flies under this tile

        const char* ab = (const char*)&As[buf][0][0];
        const char* bb = (const char*)&Bs[buf][0][0];
        i32x8 bfr[4];
#pragma unroll
        for (int nf = 0; nf < 4; ++nf) {
            i32x4 d = *(const i32x4*)(bb + (wc * 64 + nf * 16 + lr) * 64 + cb);
            bfr[nf] = (i32x8){d[0], d[1], d[2], d[3], 0, 0, 0, 0};
        }

        __builtin_amdgcn_s_setprio(1);
#pragma unroll
        for (int mf = 0; mf < 4; ++mf) {
            i32x4 d = *(const i32x4*)(ab + (wr * 64 + mf * 16 + lr) * 64 + cb);
            i32x8 af = (i32x8){d[0], d[1], d[2], d[3], 0, 0, 0, 0};
#pragma unroll
            for (int nf = 0; nf < 4; ++nf)
                acc[mf][nf] = __builtin_amdgcn_mfma_scale_f32_16x16x128_f8f6f4(
                    bfr[nf], af, acc[mf][nf],
                    4, 4,              // cbsz, blgp: fp4 / fp4
                    0, SC_W32,         // scale_a (weights, x32 undone)
                    0, SC_UNIT);       // scale_b (activations)
        }
        __builtin_amdgcn_s_setprio(0);

        __syncthreads();   // drains STG vmcnt + all ds_reads; publishes buf^1
    }
#undef STG

    // epilogue: swapped C^T frag -> lane holds 4 consecutive cols of one row
    const int c4 = (lane >> 4) << 2;
#pragma unroll
    for (int nf = 0; nf < 4; ++nf) {
        const int col0 = bcol + wc * 64 + nf * 16 + c4;
        const f32x4 bv = *(const f32x4*)&bias[col0];
#pragma unroll
        for (int mf = 0; mf < 4; ++mf) {
            const int row = brow + wr * 64 + mf * 16 + lr;
            f32x4 v = acc[mf][nf] + bv;
            if (GELU) {
#pragma unroll
                for (int rr = 0; rr < 4; ++rr) v[rr] = gelu_fast(v[rr]);
            }
            if constexpr (OUT32) {
                *(f32x4*)&((float*)Cout)[(size_t)row * N + col0] = v;
            } else {
                unsigned char* C8 = (unsigned char*)Cout;
                *(unsigned short*)&C8[((size_t)row * N + col0) >> 1] = pack_fp4x4(v);
            }
        }
    }
}

extern "C" void kernel_launch(void* const* d_in, const int* in_sizes, int n_in,
                              void* d_out, int out_size, void* d_ws, size_t ws_size,
                              hipStream_t stream) {
    const float* x  = (const float*)d_in[0];
    const float* w1 = (const float*)d_in[1];
    const float* b1 = (const float*)d_in[2];
    const float* w2 = (const float*)d_in[3];
    const float* b2 = (const float*)d_in[4];
    const float* w3 = (const float*)d_in[5];
    const float* b3 = (const float*)d_in[6];

    const int total = (out_size - B_CONST) / H_CONST;  // 32896
    float* out = (float*)d_out;
    float* out_pc = out + (size_t)total * H_CONST;

    char* ws = (char*)d_ws;
    int* valid  = (int*)ws;
    int* pc     = valid + 256;
    int* starts = pc + 256;
    int* cum    = starts + 256;
    __bf16* w1t = (__bf16*)(ws + 4096);                                 // 64 KB
    unsigned char* w2t = (unsigned char*)(w1t + (size_t)H_CONST * 32);  // 512 KB fp4
    unsigned char* w3t = w2t + (size_t)H_CONST * H_CONST / 2;           // 512 KB fp4
    unsigned char* h1  = w3t + (size_t)H_CONST * H_CONST / 2;           // total*512 B
    unsigned char* h2  = h1 + (size_t)total * H_CONST / 2;

    k_valid<<<B_CONST, 64, 0, stream>>>(x, valid);
    k_prep<<<2053, 256, 0, stream>>>(valid, pc, starts, cum, out_pc,
                                     w1, w1t, w2, w2t, w3, w3t);

    // layer 1: fused gather + K=32 bf16 GEMM, fp4 output
    dim3 g1(H_CONST / 128, total / 128);   // 8 x 257 = 2056, %8 == 0
    k_l1_fused<<<g1, dim3(256), 0, stream>>>(x, valid, cum, starts, w1t, b1, h1, total);

    // layers 2/3: MX-fp4 K=128 dbuf kernel, streamed frags, natural occupancy
    k_gemm_mx4<true,  false><<<g1, dim3(256), 0, stream>>>(h1, w2t, b2, h2, total, H_CONST, H_CONST);
    k_gemm_mx4<false, true ><<<g1, dim3(256), 0, stream>>>(h2, w3t, b3, out, total, H_CONST, H_CONST);
}

// Round 16
// 139.710 us; speedup vs baseline: 1.0714x; 1.0714x over previous
//
#include <hip/hip_runtime.h>
#include <hip/hip_bf16.h>
#include <math.h>

#define B_CONST 256
#define T_CONST 8192
#define P_CONST 16
#define H_CONST 1024

typedef __bf16 bf16x8 __attribute__((ext_vector_type(8)));
typedef __bf16 bf16x4 __attribute__((ext_vector_type(4)));
typedef float  f32x4  __attribute__((ext_vector_type(4)));
typedef int    i32x4  __attribute__((ext_vector_type(4)));
typedef int    i32x8  __attribute__((ext_vector_type(8)));

typedef __attribute__((address_space(3))) void       as3_void;
typedef const __attribute__((address_space(1))) void as1_cvoid;

__device__ __forceinline__ void gload_lds16(const void* g, void* l) {
    __builtin_amdgcn_global_load_lds((as1_cvoid*)g, (as3_void*)l, 16, 0, 0);
}

// fast gelu: x * sigmoid(1.5957691 * x * (1 + 0.044715 x^2))
__device__ __forceinline__ float gelu_fast(float x) {
    float z = 1.5957691216057308f * x * __builtin_fmaf(0.044715f, x * x, 1.0f);
    return x * __builtin_amdgcn_rcpf(1.0f + __expf(-z));
}

// fp4 e2m1 quantize (round to nearest of {0,.5,1,1.5,2,3,4,6}, sign bit 3)
__device__ __forceinline__ unsigned int f2fp4(float v) {
    float a = __builtin_fabsf(v);
    unsigned s = (__builtin_bit_cast(unsigned int, v) >> 31) << 3;
    unsigned c = (a < 0.25f) ? 0u : (a < 0.75f) ? 1u : (a < 1.25f) ? 2u :
                 (a < 1.75f) ? 3u : (a < 2.5f)  ? 4u : (a < 3.5f)  ? 5u :
                 (a < 5.0f)  ? 6u : 7u;
    return s | c;
}
__device__ __forceinline__ unsigned short pack_fp4x4(f32x4 v) {
    return (unsigned short)(f2fp4(v[0]) | (f2fp4(v[1]) << 4) |
                            (f2fp4(v[2]) << 8) | (f2fp4(v[3]) << 12));
}

// E8M0 scales, replicated bytes (op_sel=0 -> byte 0)
#define SC_UNIT 0x7F7F7F7F   // 2^0
#define SC_W32  0x7A7A7A7A   // 2^-5 (weights pre-scaled x32 at prep)

// ------------- fused prep: valid+scan (blk 0) + w1t (blk 1-4) + fp4 transposes -
// blk 0: per-batch valid via 13-step binary search on the prefix mask, then the
// pc scan (replaces the former k_valid launch; overlaps the transpose blocks).
// blk 5..1028: w2 -> w2t fp4 (x32, packed 2/byte); blk 1029..2052: w3 -> w3t.
__global__ __launch_bounds__(256) void k_prep(
    const float* __restrict__ x,
    int* __restrict__ valid, int* __restrict__ pc, int* __restrict__ starts,
    int* __restrict__ cum, float* __restrict__ out_pc,
    const float* __restrict__ w1, __bf16* __restrict__ w1t,
    const float* __restrict__ w2, unsigned char* __restrict__ w2t,
    const float* __restrict__ w3, unsigned char* __restrict__ w3t) {
    __shared__ int s[B_CONST];
    __shared__ float tile[32][33];
    const int bid = blockIdx.x;
    const int t = threadIdx.x;
    if (bid == 0) {
        // valid[t] = count of 1s = first zero position (mask is a prefix mask)
        const float* m = x + (size_t)t * (T_CONST * 2) + 1;   // mask[tt] = m[2tt]
        int lo = 0, hi = T_CONST;
        while (lo < hi) {
            int mid = (lo + hi) >> 1;
            if (m[2 * (size_t)mid] > 0.5f) lo = mid + 1; else hi = mid;
        }
        valid[t] = lo;
        int p = (lo + P_CONST - 1) / P_CONST;
        s[t] = p;
        __syncthreads();
        for (int off = 1; off < B_CONST; off <<= 1) {
            int add = (t >= off) ? s[t - off] : 0;
            __syncthreads();
            s[t] += add;
            __syncthreads();
        }
        pc[t] = p;
        cum[t] = s[t];
        starts[t] = s[t] - p;
        out_pc[t] = (float)p;
    } else if (bid <= 4) {
        int n = (bid - 1) * 256 + t;
        for (int k = 0; k < 32; ++k)
            w1t[n * 32 + k] = (k < 16) ? (__bf16)w1[k * H_CONST + n] : (__bf16)0.f;
    } else {
        int fid = bid - 5;
        const float* W = w2; unsigned char* WT = w2t;
        if (fid >= 1024) { W = w3; WT = w3t; fid -= 1024; }
        const int n0 = (fid & 31) * 32, k0 = (fid >> 5) * 32;
        const int c = t & 31, r0 = t >> 5;
        for (int r = r0; r < 32; r += 8)
            tile[r][c] = W[(size_t)(k0 + r) * H_CONST + n0 + c];
        __syncthreads();
        // write fp4-packed transposed: row n (32) x 16 bytes (32 k / 2)
        const int nl = t >> 3;          // 0..31
        const int b0 = t & 7;           // handles bytes b0 and b0+8
        unsigned char* dst = WT + (size_t)(n0 + nl) * (H_CONST / 2) + (k0 >> 1);
#pragma unroll
        for (int h = 0; h < 2; ++h) {
            int b = b0 + h * 8;
            unsigned lo = f2fp4(32.f * tile[2 * b][nl]);
            unsigned hi = f2fp4(32.f * tile[2 * b + 1][nl]);
            dst[b] = (unsigned char)(lo | (hi << 4));
        }
    }
}

// ---------------- layer-1 fused gather+GEMM (K=32 bf16), fp4 output ------------
__global__ __launch_bounds__(256) void k_l1_fused(
    const float* __restrict__ x, const int* __restrict__ valid,
    const int* __restrict__ cum, const int* __restrict__ starts,
    const __bf16* __restrict__ w1t, const float* __restrict__ bias,
    unsigned char* __restrict__ C, int total) {
    __shared__ __bf16 As[128][32];
    __shared__ __bf16 Bs[128][32];

    const int lane = threadIdx.x & 63;
    const int wid  = threadIdx.x >> 6;
    const int wr = wid >> 1, wc = wid & 1;

    const int nwg_x = gridDim.x;
    const int orig = blockIdx.y * nwg_x + blockIdx.x;
    const int cpx = (nwg_x * gridDim.y) >> 3;
    const int wgid = (orig & 7) * cpx + (orig >> 3);
    const int brow = (wgid / nwg_x) * 128;
    const int bcol = (wgid % nwg_x) * 128;

    const int sr = lane >> 2;
    const int sc = (lane & 3) * 8;
    const size_t b_base = (size_t)(bcol + wid * 16 + sr) * 32 + sc;
    gload_lds16(w1t + b_base,           &Bs[wid * 16][0]);
    gload_lds16(w1t + b_base + 64 * 32, &Bs[64 + wid * 16][0]);

    {
        const int r  = threadIdx.x >> 1;
        const int ch = threadIdx.x & 1;
        const int j  = brow + r;
        int lo = 0, hi = B_CONST - 1;
        while (lo < hi) { int mid = (lo + hi) >> 1; if (cum[mid] > j) hi = mid; else lo = mid + 1; }
        const int b = lo;
        const int p = j - starts[b];
        __bf16 vals[16];
        if (ch == 0) {
            const int vb = valid[b];
            const float* xb = x + (size_t)b * (T_CONST * 2) + 32 * p;
#pragma unroll
            for (int i = 0; i < 8; ++i) {
                float4 v = *(const float4*)(xb + 4 * i);
                int i0 = p * 16 + 2 * i;
                vals[2 * i]     = (__bf16)((i0 < vb)     ? v.x : 0.f);
                vals[2 * i + 1] = (__bf16)((i0 + 1 < vb) ? v.z : 0.f);
            }
        } else {
#pragma unroll
            for (int i = 0; i < 16; ++i) vals[i] = (__bf16)0.f;
        }
        *(bf16x8*)&As[r][ch * 16]     = *(bf16x8*)&vals[0];
        *(bf16x8*)&As[r][ch * 16 + 8] = *(bf16x8*)&vals[8];
    }
    __syncthreads();

    const int lr = lane & 15;
    const int lk = (lane >> 4) * 8;

    f32x4 acc[4][4];
#pragma unroll
    for (int i = 0; i < 4; ++i)
#pragma unroll
        for (int j = 0; j < 4; ++j)
            acc[i][j] = (f32x4){0.f, 0.f, 0.f, 0.f};

    bf16x8 af[4], bfr[4];
#pragma unroll
    for (int mf = 0; mf < 4; ++mf)
        af[mf] = *(const bf16x8*)&As[wr * 64 + mf * 16 + lr][lk];
#pragma unroll
    for (int nf = 0; nf < 4; ++nf)
        bfr[nf] = *(const bf16x8*)&Bs[wc * 64 + nf * 16 + lr][lk];
#pragma unroll
    for (int mf = 0; mf < 4; ++mf)
#pragma unroll
        for (int nf = 0; nf < 4; ++nf)
            acc[mf][nf] = __builtin_amdgcn_mfma_f32_16x16x32_bf16(
                bfr[nf], af[mf], acc[mf][nf], 0, 0, 0);

    const int c4 = (lane >> 4) << 2;
#pragma unroll
    for (int nf = 0; nf < 4; ++nf) {
        const int col0 = bcol + wc * 64 + nf * 16 + c4;
        const f32x4 bv = *(const f32x4*)&bias[col0];
#pragma unroll
        for (int mf = 0; mf < 4; ++mf) {
            const int row = brow + wr * 64 + mf * 16 + lr;
            f32x4 v = acc[mf][nf] + bv;
#pragma unroll
            for (int rr = 0; rr < 4; ++rr) v[rr] = gelu_fast(v[rr]);
            *(unsigned short*)&C[((size_t)row * H_CONST + col0) >> 1] = pack_fp4x4(v);
        }
    }
}

// ---------------- big GEMM: MX-fp4 K=128, single-buffer (R13 proven best) ------
// 128x128 tile, 4 waves 2x2, BK=128 fp4 -> 64-B LDS rows (16 KiB total),
// 2-barrier single-buffer loop, 3 blocks/CU. Slot swizzle slot^((row>>1)&3)
// both-sides (pre-swizzled global source + swizzled frag read). Fragment =
// one b128/lane (low 4 dwords of v8i32; fp4 FMT=4 reads 4 regs).
// Scales: weights E8M0 2^-5 (pre-scaled x32), activations 1.0.
template <bool GELU, bool OUT32>
__global__ __launch_bounds__(256, 3) void k_gemm_mx4(
    const unsigned char* __restrict__ A, const unsigned char* __restrict__ WT,
    const float* __restrict__ bias, void* __restrict__ Cout,
    int M, int N, int K) {
    __shared__ unsigned char As[128][64];   // 8 KiB
    __shared__ unsigned char Bs[128][64];   // 8 KiB

    const int lane = threadIdx.x & 63;
    const int wid  = threadIdx.x >> 6;
    const int wr = wid >> 1, wc = wid & 1;

    const int nwg_x = gridDim.x;
    const int orig = blockIdx.y * nwg_x + blockIdx.x;
    const int cpx = (nwg_x * gridDim.y) >> 3;   // nwg = 2056, %8 == 0
    const int wgid = (orig & 7) * cpx + (orig >> 3);
    const int brow = (wgid / nwg_x) * 128;
    const int bcol = (wgid % nwg_x) * 128;

    f32x4 acc[4][4];
#pragma unroll
    for (int i = 0; i < 4; ++i)
#pragma unroll
        for (int j = 0; j < 4; ++j)
            acc[i][j] = (f32x4){0.f, 0.f, 0.f, 0.f};

    // staging: per K-tile each wave covers 32 rows x 64 B = 2 loads per matrix.
    // 1-KB load: lane l -> row l>>2 (16 rows), slot l&3. Pre-swizzled global
    // source: fetch slot (l&3) ^ ((row>>1)&3) = (l&3) ^ ((l>>3)&3).
    const int KB = K >> 1;                           // 512 bytes/row
    const int srow = lane >> 2;
    const int sgrp = 16 * ((lane & 3) ^ ((lane >> 3) & 3));
    const unsigned char* Ab = A  + (size_t)(brow + wid * 32 + srow) * KB + sgrp;
    const unsigned char* Bb = WT + (size_t)(bcol + wid * 32 + srow) * KB + sgrp;
    const size_t r16 = (size_t)16 * KB;

#define STG(ko)                                                   \
    do {                                                          \
        gload_lds16(Ab + (ko),       &As[wid * 32][0]);           \
        gload_lds16(Ab + r16 + (ko), &As[wid * 32 + 16][0]);      \
        gload_lds16(Bb + (ko),       &Bs[wid * 32][0]);           \
        gload_lds16(Bb + r16 + (ko), &Bs[wid * 32 + 16][0]);      \
    } while (0)

    // fragment reads: op-row = frag*16 + (lane&15); lane's 32 k-elems = 16 B
    // at slot lane>>4, swizzled with (row>>1)&3 = ((lane&15)>>1)&3.
    const int lr = lane & 15;
    const int cb = ((lane >> 4) ^ ((lr >> 1) & 3)) << 4;

    const int nt = K >> 7;   // 8 K-tiles of 128
    STG(0);

    for (int t = 0; t < nt; ++t) {
        __syncthreads();                 // stage-t loads landed (vmcnt drain)

        const char* ab = (const char*)&As[0][0];
        const char* bb = (const char*)&Bs[0][0];
        i32x8 af[4], bfr[4];
#pragma unroll
        for (int mf = 0; mf < 4; ++mf) {
            i32x4 d = *(const i32x4*)(ab + (wr * 64 + mf * 16 + lr) * 64 + cb);
            af[mf] = (i32x8){d[0], d[1], d[2], d[3], 0, 0, 0, 0};
        }
#pragma unroll
        for (int nf = 0; nf < 4; ++nf) {
            i32x4 d = *(const i32x4*)(bb + (wc * 64 + nf * 16 + lr) * 64 + cb);
            bfr[nf] = (i32x8){d[0], d[1], d[2], d[3], 0, 0, 0, 0};
        }
        __syncthreads();                 // all waves done reading LDS (cheap)

        if (t + 1 < nt) STG((t + 1) * 64);   // next tile flies under the MFMAs

        __builtin_amdgcn_s_setprio(1);
#pragma unroll
        for (int mf = 0; mf < 4; ++mf)
#pragma unroll
            for (int nf = 0; nf < 4; ++nf)
                acc[mf][nf] = __builtin_amdgcn_mfma_scale_f32_16x16x128_f8f6f4(
                    bfr[nf], af[mf], acc[mf][nf],
                    4, 4,              // cbsz, blgp: fp4 / fp4
                    0, SC_W32,         // scale_a (weights, x32 undone)
                    0, SC_UNIT);       // scale_b (activations)
        __builtin_amdgcn_s_setprio(0);
    }
#undef STG

    // epilogue: swapped C^T frag -> lane holds 4 consecutive cols of one row
    const int c4 = (lane >> 4) << 2;
#pragma unroll
    for (int nf = 0; nf < 4; ++nf) {
        const int col0 = bcol + wc * 64 + nf * 16 + c4;
        const f32x4 bv = *(const f32x4*)&bias[col0];
#pragma unroll
        for (int mf = 0; mf < 4; ++mf) {
            const int row = brow + wr * 64 + mf * 16 + lr;
            f32x4 v = acc[mf][nf] + bv;
            if (GELU) {
#pragma unroll
                for (int rr = 0; rr < 4; ++rr) v[rr] = gelu_fast(v[rr]);
            }
            if constexpr (OUT32) {
                *(f32x4*)&((float*)Cout)[(size_t)row * N + col0] = v;
            } else {
                unsigned char* C8 = (unsigned char*)Cout;
                *(unsigned short*)&C8[((size_t)row * N + col0) >> 1] = pack_fp4x4(v);
            }
        }
    }
}

extern "C" void kernel_launch(void* const* d_in, const int* in_sizes, int n_in,
                              void* d_out, int out_size, void* d_ws, size_t ws_size,
                              hipStream_t stream) {
    const float* x  = (const float*)d_in[0];
    const float* w1 = (const float*)d_in[1];
    const float* b1 = (const float*)d_in[2];
    const float* w2 = (const float*)d_in[3];
    const float* b2 = (const float*)d_in[4];
    const float* w3 = (const float*)d_in[5];
    const float* b3 = (const float*)d_in[6];

    const int total = (out_size - B_CONST) / H_CONST;  // 32896
    float* out = (float*)d_out;
    float* out_pc = out + (size_t)total * H_CONST;

    char* ws = (char*)d_ws;
    int* valid  = (int*)ws;
    int* pc     = valid + 256;
    int* starts = pc + 256;
    int* cum    = starts + 256;
    __bf16* w1t = (__bf16*)(ws + 4096);                                 // 64 KB
    unsigned char* w2t = (unsigned char*)(w1t + (size_t)H_CONST * 32);  // 512 KB fp4
    unsigned char* w3t = w2t + (size_t)H_CONST * H_CONST / 2;           // 512 KB fp4
    unsigned char* h1  = w3t + (size_t)H_CONST * H_CONST / 2;           // total*512 B
    unsigned char* h2  = h1 + (size_t)total * H_CONST / 2;

    // prep: valid (binary search) + scan + all weight conversions, one launch
    k_prep<<<2053, 256, 0, stream>>>(x, valid, pc, starts, cum, out_pc,
                                     w1, w1t, w2, w2t, w3, w3t);

    // layer 1: fused gather + K=32 bf16 GEMM, fp4 output
    dim3 g1(H_CONST / 128, total / 128);   // 8 x 257 = 2056, %8 == 0
    k_l1_fused<<<g1, dim3(256), 0, stream>>>(x, valid, cum, starts, w1t, b1, h1, total);

    // layers 2/3: MX-fp4 K=128 single-buffer kernel (R13 proven), 3 blocks/CU
    k_gemm_mx4<true,  false><<<g1, dim3(256), 0, stream>>>(h1, w2t, b2, h2, total, H_CONST, H_CONST);
    k_gemm_mx4<false, true ><<<g1, dim3(256), 0, stream>>>(h2, w3t, b3, out, total, H_CONST, H_CONST);
}

// Round 17
// 136.862 us; speedup vs baseline: 1.0937x; 1.0208x over previous
//
#include <hip/hip_runtime.h>
#include <hip/hip_bf16.h>
#include <math.h>

#define B_CONST 256
#define T_CONST 8192
#define P_CONST 16
#define H_CONST 1024

typedef __bf16 bf16x8 __attribute__((ext_vector_type(8)));
typedef __bf16 bf16x4 __attribute__((ext_vector_type(4)));
typedef float  f32x4  __attribute__((ext_vector_type(4)));
typedef int    i32x4  __attribute__((ext_vector_type(4)));
typedef int    i32x8  __attribute__((ext_vector_type(8)));

typedef __attribute__((address_space(3))) void       as3_void;
typedef const __attribute__((address_space(1))) void as1_cvoid;

__device__ __forceinline__ void gload_lds16(const void* g, void* l) {
    __builtin_amdgcn_global_load_lds((as1_cvoid*)g, (as3_void*)l, 16, 0, 0);
}

// fast gelu: x * sigmoid(1.5957691 * x * (1 + 0.044715 x^2))
__device__ __forceinline__ float gelu_fast(float x) {
    float z = 1.5957691216057308f * x * __builtin_fmaf(0.044715f, x * x, 1.0f);
    return x * __builtin_amdgcn_rcpf(1.0f + __expf(-z));
}

// fp4 e2m1 quantize (round to nearest of {0,.5,1,1.5,2,3,4,6}, sign bit 3)
__device__ __forceinline__ unsigned int f2fp4(float v) {
    float a = __builtin_fabsf(v);
    unsigned s = (__builtin_bit_cast(unsigned int, v) >> 31) << 3;
    unsigned c = (a < 0.25f) ? 0u : (a < 0.75f) ? 1u : (a < 1.25f) ? 2u :
                 (a < 1.75f) ? 3u : (a < 2.5f)  ? 4u : (a < 3.5f)  ? 5u :
                 (a < 5.0f)  ? 6u : 7u;
    return s | c;
}
__device__ __forceinline__ unsigned short pack_fp4x4(f32x4 v) {
    return (unsigned short)(f2fp4(v[0]) | (f2fp4(v[1]) << 4) |
                            (f2fp4(v[2]) << 8) | (f2fp4(v[3]) << 12));
}

// E8M0 scales, replicated bytes (op_sel=0 -> byte 0)
#define SC_UNIT 0x7F7F7F7F   // 2^0
#define SC_W32  0x7A7A7A7A   // 2^-5 (weights pre-scaled x32 at prep)

// ------------- fused prep: valid+scan (blk 0) + w1t (blk 1-4) + fp4 transposes -
__global__ __launch_bounds__(256) void k_prep(
    const float* __restrict__ x,
    int* __restrict__ valid, int* __restrict__ pc, int* __restrict__ starts,
    int* __restrict__ cum, float* __restrict__ out_pc,
    const float* __restrict__ w1, __bf16* __restrict__ w1t,
    const float* __restrict__ w2, unsigned char* __restrict__ w2t,
    const float* __restrict__ w3, unsigned char* __restrict__ w3t) {
    __shared__ int s[B_CONST];
    __shared__ float tile[32][33];
    const int bid = blockIdx.x;
    const int t = threadIdx.x;
    if (bid == 0) {
        // valid[t] = first zero position (mask is a prefix mask)
        const float* m = x + (size_t)t * (T_CONST * 2) + 1;   // mask[tt] = m[2tt]
        int lo = 0, hi = T_CONST;
        while (lo < hi) {
            int mid = (lo + hi) >> 1;
            if (m[2 * (size_t)mid] > 0.5f) lo = mid + 1; else hi = mid;
        }
        valid[t] = lo;
        int p = (lo + P_CONST - 1) / P_CONST;
        s[t] = p;
        __syncthreads();
        for (int off = 1; off < B_CONST; off <<= 1) {
            int add = (t >= off) ? s[t - off] : 0;
            __syncthreads();
            s[t] += add;
            __syncthreads();
        }
        pc[t] = p;
        cum[t] = s[t];
        starts[t] = s[t] - p;
        out_pc[t] = (float)p;
    } else if (bid <= 4) {
        int n = (bid - 1) * 256 + t;
        for (int k = 0; k < 32; ++k)
            w1t[n * 32 + k] = (k < 16) ? (__bf16)w1[k * H_CONST + n] : (__bf16)0.f;
    } else {
        int fid = bid - 5;
        const float* W = w2; unsigned char* WT = w2t;
        if (fid >= 1024) { W = w3; WT = w3t; fid -= 1024; }
        const int n0 = (fid & 31) * 32, k0 = (fid >> 5) * 32;
        const int c = t & 31, r0 = t >> 5;
        for (int r = r0; r < 32; r += 8)
            tile[r][c] = W[(size_t)(k0 + r) * H_CONST + n0 + c];
        __syncthreads();
        // write fp4-packed transposed: row n (32) x 16 bytes (32 k / 2)
        const int nl = t >> 3;          // 0..31
        const int b0 = t & 7;           // handles bytes b0 and b0+8
        unsigned char* dst = WT + (size_t)(n0 + nl) * (H_CONST / 2) + (k0 >> 1);
#pragma unroll
        for (int h = 0; h < 2; ++h) {
            int b = b0 + h * 8;
            unsigned lo = f2fp4(32.f * tile[2 * b][nl]);
            unsigned hi = f2fp4(32.f * tile[2 * b + 1][nl]);
            dst[b] = (unsigned char)(lo | (hi << 4));
        }
    }
}

// ---------------- layer-1 fused gather+GEMM (K=32 bf16), fp4 output ------------
__global__ __launch_bounds__(256) void k_l1_fused(
    const float* __restrict__ x, const int* __restrict__ valid,
    const int* __restrict__ cum, const int* __restrict__ starts,
    const __bf16* __restrict__ w1t, const float* __restrict__ bias,
    unsigned char* __restrict__ C, int total) {
    __shared__ __bf16 As[128][32];
    __shared__ __bf16 Bs[128][32];

    const int lane = threadIdx.x & 63;
    const int wid  = threadIdx.x >> 6;
    const int wr = wid >> 1, wc = wid & 1;

    const int nwg_x = gridDim.x;
    const int orig = blockIdx.y * nwg_x + blockIdx.x;
    const int cpx = (nwg_x * gridDim.y) >> 3;
    const int wgid = (orig & 7) * cpx + (orig >> 3);
    const int brow = (wgid / nwg_x) * 128;
    const int bcol = (wgid % nwg_x) * 128;

    const int sr = lane >> 2;
    const int sc = (lane & 3) * 8;
    const size_t b_base = (size_t)(bcol + wid * 16 + sr) * 32 + sc;
    gload_lds16(w1t + b_base,           &Bs[wid * 16][0]);
    gload_lds16(w1t + b_base + 64 * 32, &Bs[64 + wid * 16][0]);

    {
        const int r  = threadIdx.x >> 1;
        const int ch = threadIdx.x & 1;
        const int j  = brow + r;
        int lo = 0, hi = B_CONST - 1;
        while (lo < hi) { int mid = (lo + hi) >> 1; if (cum[mid] > j) hi = mid; else lo = mid + 1; }
        const int b = lo;
        const int p = j - starts[b];
        __bf16 vals[16];
        if (ch == 0) {
            const int vb = valid[b];
            const float* xb = x + (size_t)b * (T_CONST * 2) + 32 * p;
#pragma unroll
            for (int i = 0; i < 8; ++i) {
                float4 v = *(const float4*)(xb + 4 * i);
                int i0 = p * 16 + 2 * i;
                vals[2 * i]     = (__bf16)((i0 < vb)     ? v.x : 0.f);
                vals[2 * i + 1] = (__bf16)((i0 + 1 < vb) ? v.z : 0.f);
            }
        } else {
#pragma unroll
            for (int i = 0; i < 16; ++i) vals[i] = (__bf16)0.f;
        }
        *(bf16x8*)&As[r][ch * 16]     = *(bf16x8*)&vals[0];
        *(bf16x8*)&As[r][ch * 16 + 8] = *(bf16x8*)&vals[8];
    }
    __syncthreads();

    const int lr = lane & 15;
    const int lk = (lane >> 4) * 8;

    f32x4 acc[4][4];
#pragma unroll
    for (int i = 0; i < 4; ++i)
#pragma unroll
        for (int j = 0; j < 4; ++j)
            acc[i][j] = (f32x4){0.f, 0.f, 0.f, 0.f};

    bf16x8 af[4], bfr[4];
#pragma unroll
    for (int mf = 0; mf < 4; ++mf)
        af[mf] = *(const bf16x8*)&As[wr * 64 + mf * 16 + lr][lk];
#pragma unroll
    for (int nf = 0; nf < 4; ++nf)
        bfr[nf] = *(const bf16x8*)&Bs[wc * 64 + nf * 16 + lr][lk];
#pragma unroll
    for (int mf = 0; mf < 4; ++mf)
#pragma unroll
        for (int nf = 0; nf < 4; ++nf)
            acc[mf][nf] = __builtin_amdgcn_mfma_f32_16x16x32_bf16(
                bfr[nf], af[mf], acc[mf][nf], 0, 0, 0);

    const int c4 = (lane >> 4) << 2;
#pragma unroll
    for (int nf = 0; nf < 4; ++nf) {
        const int col0 = bcol + wc * 64 + nf * 16 + c4;
        const f32x4 bv = *(const f32x4*)&bias[col0];
#pragma unroll
        for (int mf = 0; mf < 4; ++mf) {
            const int row = brow + wr * 64 + mf * 16 + lr;
            f32x4 v = acc[mf][nf] + bv;
#pragma unroll
            for (int rr = 0; rr < 4; ++rr) v[rr] = gelu_fast(v[rr]);
            *(unsigned short*)&C[((size_t)row * H_CONST + col0) >> 1] = pack_fp4x4(v);
        }
    }
}

// ---------------- big GEMM: MX-fp4 BK=256 single-buffer ------------------------
// Halves the per-tile overhead payments vs R13 (nt 8 -> 4; 32 MFMA per 2
// barriers, the ratio that won at bf16/R6). LDS 2 x 16 KiB = 32 KiB -> still
// 3 blocks/CU. 128-B LDS rows -> byte-identical swizzle to the R12 fp8 kernel
// (slot ^ (row&7), proven 0-conflict; frag-read uniformity: 8 lanes/16B slot
// = 2 lanes/bank = free). Staging = R12's 8-row-chunk pattern. Both kk halves
// read to regs before sync2 (single-buffer WAR discipline, R13-proven).
// Scales: weights E8M0 2^-5 (pre-scaled x32), activations 1.0.
template <bool GELU, bool OUT32>
__global__ __launch_bounds__(256, 3) void k_gemm_mx4(
    const unsigned char* __restrict__ A, const unsigned char* __restrict__ WT,
    const float* __restrict__ bias, void* __restrict__ Cout,
    int M, int N, int K) {
    __shared__ unsigned char As[128][128];   // 16 KiB
    __shared__ unsigned char Bs[128][128];   // 16 KiB

    const int lane = threadIdx.x & 63;
    const int wid  = threadIdx.x >> 6;
    const int wr = wid >> 1, wc = wid & 1;

    const int nwg_x = gridDim.x;
    const int orig = blockIdx.y * nwg_x + blockIdx.x;
    const int cpx = (nwg_x * gridDim.y) >> 3;   // nwg = 2056, %8 == 0
    const int wgid = (orig & 7) * cpx + (orig >> 3);
    const int brow = (wgid / nwg_x) * 128;
    const int bcol = (wgid % nwg_x) * 128;

    f32x4 acc[4][4];
#pragma unroll
    for (int i = 0; i < 4; ++i)
#pragma unroll
        for (int j = 0; j < 4; ++j)
            acc[i][j] = (f32x4){0.f, 0.f, 0.f, 0.f};

    // staging: per K-tile each wave covers 32 rows x 128 B = 4 loads per
    // matrix, 8-row chunks. 1-KB load: lane l -> row l>>3, slot l&7.
    // Pre-swizzled global source: fetch slot (l&7) ^ ((l>>3)&7) [= row&7].
    const int KB = K >> 1;                           // 512 bytes/row
    const int lr8 = lane >> 3;                       // 0..7
    const int sgrp = 16 * ((lane & 7) ^ lr8);
    const unsigned char* Ab = A  + (size_t)(brow + wid * 32 + lr8) * KB + sgrp;
    const unsigned char* Bb = WT + (size_t)(bcol + wid * 32 + lr8) * KB + sgrp;
    const size_t r8 = (size_t)8 * KB;

#define STG(ko)                                                       \
    do {                                                              \
        gload_lds16(Ab + (ko),          &As[wid * 32][0]);            \
        gload_lds16(Ab + r8 + (ko),     &As[wid * 32 + 8][0]);        \
        gload_lds16(Ab + 2 * r8 + (ko), &As[wid * 32 + 16][0]);       \
        gload_lds16(Ab + 3 * r8 + (ko), &As[wid * 32 + 24][0]);       \
        gload_lds16(Bb + (ko),          &Bs[wid * 32][0]);            \
        gload_lds16(Bb + r8 + (ko),     &Bs[wid * 32 + 8][0]);        \
        gload_lds16(Bb + 2 * r8 + (ko), &Bs[wid * 32 + 16][0]);       \
        gload_lds16(Bb + 3 * r8 + (ko), &Bs[wid * 32 + 24][0]);       \
    } while (0)

    // fragment reads: op-row = frag*16 + (lane&15); for K-half kk the lane's
    // 32 k-elems = 16 B at slot kk*4 + (lane>>4), swizzled ^ (row&7) = (lr&7).
    const int lr = lane & 15;
    const int g  = lane >> 4;
    const int rs = lr & 7;
    const int cb0 = ((g)     ^ rs) << 4;   // kk=0 slot
    const int cb1 = ((4 + g) ^ rs) << 4;   // kk=1 slot

    const int nt = K >> 8;   // 4 K-tiles of 256
    STG(0);

    for (int t = 0; t < nt; ++t) {
        __syncthreads();                 // stage-t loads landed (vmcnt drain)

        const char* ab = (const char*)&As[0][0];
        const char* bb = (const char*)&Bs[0][0];
        i32x4 af[2][4], bfr[2][4];
#pragma unroll
        for (int mf = 0; mf < 4; ++mf) {
            const int rb = (wr * 64 + mf * 16 + lr) * 128;
            af[0][mf] = *(const i32x4*)(ab + rb + cb0);
            af[1][mf] = *(const i32x4*)(ab + rb + cb1);
        }
#pragma unroll
        for (int nf = 0; nf < 4; ++nf) {
            const int rb = (wc * 64 + nf * 16 + lr) * 128;
            bfr[0][nf] = *(const i32x4*)(bb + rb + cb0);
            bfr[1][nf] = *(const i32x4*)(bb + rb + cb1);
        }
        __syncthreads();                 // all waves done reading LDS (cheap)

        if (t + 1 < nt) STG((t + 1) * 128);  // next tile flies under the MFMAs

        __builtin_amdgcn_s_setprio(1);
#pragma unroll
        for (int kk = 0; kk < 2; ++kk)
#pragma unroll
            for (int mf = 0; mf < 4; ++mf) {
                i32x4 a4 = af[kk][mf];
                i32x8 a8 = (i32x8){a4[0], a4[1], a4[2], a4[3], 0, 0, 0, 0};
#pragma unroll
                for (int nf = 0; nf < 4; ++nf) {
                    i32x4 b4 = bfr[kk][nf];
                    i32x8 b8 = (i32x8){b4[0], b4[1], b4[2], b4[3], 0, 0, 0, 0};
                    acc[mf][nf] = __builtin_amdgcn_mfma_scale_f32_16x16x128_f8f6f4(
                        b8, a8, acc[mf][nf],
                        4, 4,              // cbsz, blgp: fp4 / fp4
                        0, SC_W32,         // scale_a (weights, x32 undone)
                        0, SC_UNIT);       // scale_b (activations)
                }
            }
        __builtin_amdgcn_s_setprio(0);
    }
#undef STG

    // epilogue: swapped C^T frag -> lane holds 4 consecutive cols of one row
    const int c4 = (lane >> 4) << 2;
#pragma unroll
    for (int nf = 0; nf < 4; ++nf) {
        const int col0 = bcol + wc * 64 + nf * 16 + c4;
        const f32x4 bv = *(const f32x4*)&bias[col0];
#pragma unroll
        for (int mf = 0; mf < 4; ++mf) {
            const int row = brow + wr * 64 + mf * 16 + lr;
            f32x4 v = acc[mf][nf] + bv;
            if (GELU) {
#pragma unroll
                for (int rr = 0; rr < 4; ++rr) v[rr] = gelu_fast(v[rr]);
            }
            if constexpr (OUT32) {
                *(f32x4*)&((float*)Cout)[(size_t)row * N + col0] = v;
            } else {
                unsigned char* C8 = (unsigned char*)Cout;
                *(unsigned short*)&C8[((size_t)row * N + col0) >> 1] = pack_fp4x4(v);
            }
        }
    }
}

extern "C" void kernel_launch(void* const* d_in, const int* in_sizes, int n_in,
                              void* d_out, int out_size, void* d_ws, size_t ws_size,
                              hipStream_t stream) {
    const float* x  = (const float*)d_in[0];
    const float* w1 = (const float*)d_in[1];
    const float* b1 = (const float*)d_in[2];
    const float* w2 = (const float*)d_in[3];
    const float* b2 = (const float*)d_in[4];
    const float* w3 = (const float*)d_in[5];
    const float* b3 = (const float*)d_in[6];

    const int total = (out_size - B_CONST) / H_CONST;  // 32896
    float* out = (float*)d_out;
    float* out_pc = out + (size_t)total * H_CONST;

    char* ws = (char*)d_ws;
    int* valid  = (int*)ws;
    int* pc     = valid + 256;
    int* starts = pc + 256;
    int* cum    = starts + 256;
    __bf16* w1t = (__bf16*)(ws + 4096);                                 // 64 KB
    unsigned char* w2t = (unsigned char*)(w1t + (size_t)H_CONST * 32);  // 512 KB fp4
    unsigned char* w3t = w2t + (size_t)H_CONST * H_CONST / 2;           // 512 KB fp4
    unsigned char* h1  = w3t + (size_t)H_CONST * H_CONST / 2;           // total*512 B
    unsigned char* h2  = h1 + (size_t)total * H_CONST / 2;

    // prep: valid (binary search) + scan + all weight conversions, one launch
    k_prep<<<2053, 256, 0, stream>>>(x, valid, pc, starts, cum, out_pc,
                                     w1, w1t, w2, w2t, w3, w3t);

    // layer 1: fused gather + K=32 bf16 GEMM, fp4 output
    dim3 g1(H_CONST / 128, total / 128);   // 8 x 257 = 2056, %8 == 0
    k_l1_fused<<<g1, dim3(256), 0, stream>>>(x, valid, cum, starts, w1t, b1, h1, total);

    // layers 2/3: MX-fp4 BK=256 single-buffer kernel, 3 blocks/CU
    k_gemm_mx4<true,  false><<<g1, dim3(256), 0, stream>>>(h1, w2t, b2, h2, total, H_CONST, H_CONST);
    k_gemm_mx4<false, true ><<<g1, dim3(256), 0, stream>>>(h2, w3t, b3, out, total, H_CONST, H_CONST);
}